// Round 1
// 247.170 us; speedup vs baseline: 1.0183x; 1.0183x over previous
//
#include <hip/hip_runtime.h>
#include <hip/hip_fp16.h>
#include <math.h>

// MSMOM: multi-scale soft morphological opening + BN/ReLU + 1x1 conv + BN/ReLU
// B=4, C=64, H=W=256, k=3, dilations 1..4, beta=15.
//
// Morph computed in exp2-domain: soft-ero/dil are linear correlations on
// P = 2^{-K x} (K = beta*log2e).  S1 = sum W*P  ->  2^{K e} = 1/S1 (rcp);
// dilation: out = C1*log2( sum Wd * (1/S1) ).  No per-pixel max needed:
// 2^{-Kx} spans 2^+-119 (x ~ N(0,1)) and 2^{Ke} spans ~2^[-108,43], both
// within fp32.  Flush-to-zero corner cases land on relu-0-correct outputs.

constexpr int C_ = 64, H_ = 256, W_ = 256;
constexpr int HW = H_ * W_;
constexpr float EPSV = 1e-5f;
constexpr float KL2E = 21.64042561333445f;    // beta * log2(e)
constexpr float C1   = 0.046209812037329684f; // ln(2) / beta

typedef __attribute__((ext_vector_type(8))) _Float16 half8v;
typedef __attribute__((ext_vector_type(4))) float f32x4;

__device__ _Float16 g_wh[64 * 256];  // conv weights fp16, row-major [o][c]
__device__ float g_scale[64];
__device__ float g_shift[64];
__device__ float g_we9e[4 * 64 * 9]; // 2^{K*we}  (morph erosion weights, exp2-domain)
__device__ float g_wd9e[4 * 64 * 9]; // 2^{K*wd}  (morph dilation weights, exp2-domain)
__device__ float g_cs[4 * 64];       // C1 * bn_scale  (per d,c)
__device__ float g_sh[4 * 64];       // bn shift       (per d,c)

__global__ __launch_bounds__(256) void prep(
    const float* __restrict__ cw, const float* __restrict__ g,
    const float* __restrict__ bb, const float* __restrict__ bm,
    const float* __restrict__ bv, const float* __restrict__ we,
    const float* __restrict__ wd, const float* __restrict__ bng,
    const float* __restrict__ bnb, const float* __restrict__ bnm,
    const float* __restrict__ bnv)
{
    int i = blockIdx.x * 256 + threadIdx.x;  // 16384 total
    g_wh[i] = (_Float16)cw[i];
    if (i < 64) {
        float s = g[i] * rsqrtf(bv[i] + EPSV);
        g_scale[i] = s;
        g_shift[i] = bb[i] - bm[i] * s;
    }
    if (i < 2304) {  // 4*64*9 morph weights, exp2-domain (hoisted out of morph_all)
        g_we9e[i] = __builtin_amdgcn_exp2f(KL2E * we[i]);
        g_wd9e[i] = __builtin_amdgcn_exp2f(KL2E * wd[i]);
    }
    if (i < 256) {   // per-(d,c) BN constants
        float s = bng[i] * rsqrtf(bnv[i] + EPSV);
        g_cs[i] = C1 * s;
        g_sh[i] = bnb[i] - bnm[i] * s;
    }
}

// One block = one 64x64 tile of one (b,c); all 4 dilations reuse staged P.
// xs: P = 2^{-K x}, 80 rows x 80 cols, stride 92 (28 mod 32 -> row bank
// offsets cycle uniformly over all 8 cosets).  es: 2^{K e}, 72 rows x 72
// cols, stride 76 (12 mod 32 -> also all 8 cosets; dilation never reads
// cols >71, and the erosion's last col-group writes only cols 64..71).
// LDS total 51328 B < 160K/3 -> 3 blocks/CU (was 53760 B -> 2 blocks/CU).
// 16-px-per-lane groups: tap window for any D<=4 is 6 aligned f32x4 at the
// group base ((4-D)+15+2D <= 23).  Erosion is column-major (64 consecutive
// rows per wave -> bank-uniform); dilation is 16 rows x 4 col-groups.
__global__ __launch_bounds__(256) void morph_all(
    const float* __restrict__ x, _Float16* __restrict__ cat)
{
    __shared__ __align__(16) float xs[80 * 92];
    __shared__ __align__(16) float es[72 * 76];
    const int tid = threadIdx.x;
    const int tileW = blockIdx.x & 3, tileH = blockIdx.x >> 2;  // 4x4 tiles
    const int c = blockIdx.y, b = blockIdx.z;
    const int h0 = tileH * 64, w0 = tileW * 64;
    const float* xc = x + (b * C_ + c) * HW;

    // staging: P = 2^{-K x}; out-of-image -> 0 (== 2^{-K*BIG} exactly).
    // 80 rows x 20 float4-groups; group col-validity is all-or-nothing.
    for (int u = tid; u < 1600; u += 256) {
        int r = u / 20, q4 = (u - r * 20) * 4;
        int gh = h0 - 8 + r, gw = w0 - 8 + q4;
        int ch = min(max(gh, 0), 255), cwi = min(max(gw, 0), 252);
        const float4 v = *(const float4*)&xc[ch * W_ + cwi];
        bool ok = ((unsigned)gh < 256u) && ((unsigned)gw < 253u);
        float4 sv;
        sv.x = ok ? __builtin_amdgcn_exp2f(-KL2E * v.x) : 0.f;
        sv.y = ok ? __builtin_amdgcn_exp2f(-KL2E * v.y) : 0.f;
        sv.z = ok ? __builtin_amdgcn_exp2f(-KL2E * v.z) : 0.f;
        sv.w = ok ? __builtin_amdgcn_exp2f(-KL2E * v.w) : 0.f;
        *(float4*)&xs[r * 92 + q4] = sv;
    }

    #pragma unroll
    for (int d = 0; d < 4; d++) {
        const int D = d + 1;
        const int bc = d * C_ + c;

        // weights + BN constants: precomputed in prep, wave-uniform loads
        float w9[9], wd9[9];
        #pragma unroll
        for (int i = 0; i < 9; i++) {
            w9[i]  = g_we9e[bc * 9 + i];
            wd9[i] = g_wd9e[bc * 9 + i];
        }
        const float cs = g_cs[bc];
        const float shift = g_sh[bc];

        __syncthreads();  // staging done / previous dilation reads of es done

        // erosion: 5 col-groups x 72 rows, column-major (bank-uniform).
        // es row a <-> image row h0-4+a <-> xs row a+4.
        for (int g = tid; g < 360; g += 256) {
            const int col = g / 72;            // wave-uniform-ish
            const int row = g - col * 72;
            const int qa0 = col * 16;
            float s16[16];
            #pragma unroll
            for (int p = 0; p < 16; p++) s16[p] = 0.f;
            #pragma unroll
            for (int i = 0; i < 3; i++) {
                const f32x4* xr = (const f32x4*)&xs[(row + 4 + (i - 1) * D) * 92 + qa0];
                f32x4 xw[6];
                #pragma unroll
                for (int k = 0; k < 6; k++) xw[k] = xr[k];
                #pragma unroll
                for (int j = 0; j < 3; j++) {
                    const float wv = w9[i * 3 + j];
                    #pragma unroll
                    for (int p = 0; p < 16; p++) {
                        const int wi = (4 - D) + p + j * D;  // compile-time
                        s16[p] = fmaf(wv, xw[wi >> 2][wi & 3], s16[p]);
                    }
                }
            }
            const bool rowok = (unsigned)(h0 + row - 4) < 256u;
            const int gw0 = w0 + qa0 - 4;
            f32x4 ev[4];
            #pragma unroll
            for (int p = 0; p < 16; p++) {
                float gv = __builtin_amdgcn_rcpf(fmaxf(s16[p], 1e-38f));
                bool ok = rowok && ((unsigned)(gw0 + p) < 256u);
                ev[p >> 2][p & 3] = ok ? gv : 0.f;  // pad: 2^{K*(-BIG)} = 0
            }
            f32x4* ep = (f32x4*)&es[row * 76 + qa0];
            ep[0] = ev[0]; ep[1] = ev[1];
            if (qa0 < 64) { ep[2] = ev[2]; ep[3] = ev[3]; }  // cols 72..79 never read
        }

        __syncthreads();  // es ready

        // dilation: 64 rows x 4 col-groups of 16 px, one group per thread
        {
            const int dr = tid >> 2, dq0 = (tid & 3) * 16;
            float s16[16];
            #pragma unroll
            for (int p = 0; p < 16; p++) s16[p] = 0.f;
            #pragma unroll
            for (int i = 0; i < 3; i++) {
                const f32x4* er = (const f32x4*)&es[(dr + 4 + (i - 1) * D) * 76 + dq0];
                f32x4 ew[6];
                #pragma unroll
                for (int k = 0; k < 6; k++) ew[k] = er[k];
                #pragma unroll
                for (int j = 0; j < 3; j++) {
                    const float wv = wd9[i * 3 + j];
                    #pragma unroll
                    for (int p = 0; p < 16; p++) {
                        const int wi = (4 - D) + p + j * D;
                        s16[p] = fmaf(wv, ew[wi >> 2][wi & 3], s16[p]);
                    }
                }
            }
            half8v hv0, hv1;
            #pragma unroll
            for (int p = 0; p < 16; p++) {
                float y = __builtin_amdgcn_logf(fmaxf(s16[p], 1e-38f)) * cs + shift;
                y = fmaxf(0.f, y);
                if (p < 8) hv0[p] = (_Float16)y; else hv1[p - 8] = (_Float16)y;
            }
            _Float16* cp = &cat[((size_t)((b * 4 + d) * C_ + c)) * HW
                                + (h0 + dr) * W_ + (w0 + dq0)];
            *(half8v*)cp = hv0;
            *(half8v*)(cp + 8) = hv1;
        }
    }
}

// Out[64 x 65536] = W[64x256] * Cat[256x65536] per batch via mfma_f32_16x16x32_f16.
// Double-buffered LDS staging (1 sync/kc), prefetch depth 2.  T stride 258
// halves: B-frag ds_read_u16 quads land 8 banks apart, px pairs share a dword.
// Prefetch is issued AFTER __syncthreads so the compiler's vmcnt(0) barrier
// drain only waits on loads issued one full iteration earlier (latency hidden
// under the previous MFMA phase), not on the freshly-issued HBM loads.
__global__ __launch_bounds__(256) void conv_mfma(
    const _Float16* __restrict__ cat, float* __restrict__ out)
{
    __shared__ _Float16 T[2][32 * 258];
    const int tid = threadIdx.x;
    const int lane = tid & 63, wave = tid >> 6;
    const int m = lane & 15, quad = lane >> 4;
    const int b = blockIdx.y;
    const int px0 = blockIdx.x * 256;
    const _Float16* catb = cat + (size_t)b * 256 * HW + px0;

    const int cl = tid >> 3;          // staged c row: 0..31
    const int px8 = (tid & 7) * 8;    // staged px base within 64-px strip

    f32x4 acc[4][4];
    #pragma unroll
    for (int ot = 0; ot < 4; ot++)
        #pragma unroll
        for (int pt = 0; pt < 4; pt++)
            acc[ot][pt] = (f32x4){0.f, 0.f, 0.f, 0.f};

    half8v sv[2][4];
    #pragma unroll
    for (int p = 0; p < 4; p++) {
        sv[0][p] = *(const half8v*)&catb[(size_t)cl * HW + p * 64 + px8];
        sv[1][p] = *(const half8v*)&catb[(size_t)(32 + cl) * HW + p * 64 + px8];
    }

    #pragma unroll
    for (int kc = 0; kc < 8; kc++) {
        const int buf = kc & 1;
        const int c0 = kc * 32;
        // write staged chunk (loaded 2 iterations ago)
        #pragma unroll
        for (int p = 0; p < 4; p++) {
            uint* tw = (uint*)&T[buf][cl * 258 + p * 64 + px8];
            const uint* svw = (const uint*)&sv[buf][p];
            tw[0] = svw[0]; tw[1] = svw[1]; tw[2] = svw[2]; tw[3] = svw[3];
        }
        __syncthreads();  // T[buf] ready (drain sees no fresh global loads)

        // issue prefetch for kc+2 (lands during this kc's MFMA + next kc's writes)
        if (kc < 6) {
            #pragma unroll
            for (int p = 0; p < 4; p++)
                sv[buf][p] = *(const half8v*)&catb[(size_t)(c0 + 64 + cl) * HW + p * 64 + px8];
        }

        half8v a0 = *(const half8v*)&g_wh[(0  + m) * 256 + c0 + quad * 8];
        half8v a1 = *(const half8v*)&g_wh[(16 + m) * 256 + c0 + quad * 8];
        half8v a2 = *(const half8v*)&g_wh[(32 + m) * 256 + c0 + quad * 8];
        half8v a3 = *(const half8v*)&g_wh[(48 + m) * 256 + c0 + quad * 8];

        #pragma unroll
        for (int pt = 0; pt < 4; pt++) {
            const int pxl = wave * 64 + pt * 16 + m;
            const int tb = quad * 8 * 258 + pxl;
            half8v bf;
            #pragma unroll
            for (int j = 0; j < 8; j++)
                bf[j] = T[buf][tb + j * 258];
            acc[0][pt] = __builtin_amdgcn_mfma_f32_16x16x32_f16(a0, bf, acc[0][pt], 0, 0, 0);
            acc[1][pt] = __builtin_amdgcn_mfma_f32_16x16x32_f16(a1, bf, acc[1][pt], 0, 0, 0);
            acc[2][pt] = __builtin_amdgcn_mfma_f32_16x16x32_f16(a2, bf, acc[2][pt], 0, 0, 0);
            acc[3][pt] = __builtin_amdgcn_mfma_f32_16x16x32_f16(a3, bf, acc[3][pt], 0, 0, 0);
        }
    }

    // D layout: row(o) = quad*4 + reg, col(px) = m
    #pragma unroll
    for (int ot = 0; ot < 4; ot++)
        #pragma unroll
        for (int reg = 0; reg < 4; reg++) {
            const int o = ot * 16 + quad * 4 + reg;
            const float sc = g_scale[o], sh = g_shift[o];
            float* ob = out + ((size_t)(b * 64 + o)) * HW + px0;
            #pragma unroll
            for (int pt = 0; pt < 4; pt++) {
                const int pxl = wave * 64 + pt * 16 + m;
                ob[pxl] = fmaxf(0.f, acc[ot][pt][reg] * sc + sh);
            }
        }
}

extern "C" void kernel_launch(void* const* d_in, const int* in_sizes, int n_in,
                              void* d_out, int out_size, void* d_ws, size_t ws_size,
                              hipStream_t stream)
{
    const float* x   = (const float*)d_in[0];
    const float* we  = (const float*)d_in[1];
    const float* wd  = (const float*)d_in[2];
    const float* bng = (const float*)d_in[3];
    const float* bnb = (const float*)d_in[4];
    const float* bnm = (const float*)d_in[5];
    const float* bnv = (const float*)d_in[6];
    const float* cw  = (const float*)d_in[7];
    const float* fg  = (const float*)d_in[8];
    const float* fb  = (const float*)d_in[9];
    const float* fm  = (const float*)d_in[10];
    const float* fv  = (const float*)d_in[11];
    float* out = (float*)d_out;
    _Float16* cat = (_Float16*)d_ws;  // 4*256*65536*2 B = 128 MiB

    prep<<<64, 256, 0, stream>>>(cw, fg, fb, fm, fv, we, wd, bng, bnb, bnm, bnv);
    morph_all<<<dim3(16, 64, 4), 256, 0, stream>>>(x, cat);
    conv_mfma<<<dim3(256, 4), 256, 0, stream>>>(cat, out);
}